// Round 1
// baseline (751.078 us; speedup 1.0000x reference)
//
#include <hip/hip_runtime.h>
#include <cstdint>
#include <cstddef>

// ---------------------------------------------------------------------------
// MoE encoder layer: x[4,1024,1024] fp32, top-2 of 8 experts, D=1024, F=4096.
// Strategy: fp32 router (exact top-k), deterministic bucket scatter,
// bf16 MFMA grouped GEMMs (16x16x32, 128x128 tiles, global_load_lds staging),
// fused residual+LayerNorm. aux loss -> d_out[T*D].
// ---------------------------------------------------------------------------

#define T_TOK 4096
#define DM 1024
#define DF 4096
#define NE 8
#define CAP 9216      // 8192 slots + 8*128 padding headroom
#define MAXMT 72      // max 128-row M-tiles: 64 + 8

typedef __bf16 bf16;
typedef __bf16 bf16x4 __attribute__((ext_vector_type(4)));
typedef __bf16 bf16x8 __attribute__((ext_vector_type(8)));
typedef float f32x4 __attribute__((ext_vector_type(4)));

struct Meta {
  int pad_off[NE + 1];   // 128-aligned slot region start per expert
  int n_mtiles;
  int tile_e[80];
  int tile_m0[80];
};

// ---------------- router: logits, softmax probs, top-2 ---------------------
__global__ __launch_bounds__(256) void router_kernel(
    const float* __restrict__ x, const float* __restrict__ Wg,
    int* __restrict__ topi, float* __restrict__ topw, float* __restrict__ probs) {
  int wave = threadIdx.x >> 6, lane = threadIdx.x & 63;
  int t = blockIdx.x * 4 + wave;
  const float* xr = x + (size_t)t * DM;
  float acc[NE];
#pragma unroll
  for (int e = 0; e < NE; e++) acc[e] = 0.f;
  for (int d0 = 0; d0 < DM; d0 += 64) {
    float xv = xr[d0 + lane];
    const float4* wrow = (const float4*)(Wg + (size_t)(d0 + lane) * NE);
    float4 w0 = wrow[0], w1 = wrow[1];
    acc[0] += xv * w0.x; acc[1] += xv * w0.y; acc[2] += xv * w0.z; acc[3] += xv * w0.w;
    acc[4] += xv * w1.x; acc[5] += xv * w1.y; acc[6] += xv * w1.z; acc[7] += xv * w1.w;
  }
#pragma unroll
  for (int off = 32; off >= 1; off >>= 1) {
#pragma unroll
    for (int e = 0; e < NE; e++) acc[e] += __shfl_xor(acc[e], off);
  }
  if (lane == 0) {
    float m = acc[0];
#pragma unroll
    for (int e = 1; e < NE; e++) m = fmaxf(m, acc[e]);
    float p[NE], s = 0.f;
#pragma unroll
    for (int e = 0; e < NE; e++) { p[e] = expf(acc[e] - m); s += p[e]; }
    float inv = 1.f / s;
#pragma unroll
    for (int e = 0; e < NE; e++) { p[e] *= inv; probs[t * NE + e] = p[e]; }
    // top-2 on logits (same ordering as probs; ties -> lowest index, like lax.top_k)
    int i1 = 0; float v1 = acc[0];
#pragma unroll
    for (int e = 1; e < NE; e++) if (acc[e] > v1) { v1 = acc[e]; i1 = e; }
    int i2 = -1; float v2 = -1e30f;
#pragma unroll
    for (int e = 0; e < NE; e++) if (e != i1 && acc[e] > v2) { v2 = acc[e]; i2 = e; }
    float sw = p[i1] + p[i2];
    topi[t * 2] = i1; topi[t * 2 + 1] = i2;
    topw[t * 2] = p[i1] / sw; topw[t * 2 + 1] = p[i2] / sw;
  }
}

// -------- prep: counts, aux loss, padded offsets, M-tile table (1 block) ----
__global__ __launch_bounds__(256) void prep_kernel(
    const int* __restrict__ topi, const float* __restrict__ probs,
    Meta* __restrict__ meta, float* __restrict__ aux_out) {
  __shared__ int scnt[NE];
  __shared__ float wps[4][NE];
  int tid = threadIdx.x, lane = tid & 63, wave = tid >> 6;
  if (tid < NE) scnt[tid] = 0;
  __syncthreads();
  for (int i = tid; i < T_TOK * 2; i += 256) atomicAdd(&scnt[topi[i]], 1);
  float lp[NE];
#pragma unroll
  for (int e = 0; e < NE; e++) lp[e] = 0.f;
  for (int tt = tid; tt < T_TOK; tt += 256) {
#pragma unroll
    for (int e = 0; e < NE; e++) lp[e] += probs[tt * NE + e];
  }
#pragma unroll
  for (int off = 32; off >= 1; off >>= 1) {
#pragma unroll
    for (int e = 0; e < NE; e++) lp[e] += __shfl_xor(lp[e], off);
  }
  if (lane == 0) {
#pragma unroll
    for (int e = 0; e < NE; e++) wps[wave][e] = lp[e];
  }
  __syncthreads();
  if (tid == 0) {
    float aux = 0.f;
    int nt = 0, po = 0;
    for (int e = 0; e < NE; e++) {
      float ps = wps[0][e] + wps[1][e] + wps[2][e] + wps[3][e];
      aux += (float)scnt[e] * ps;
      meta->pad_off[e] = po;
      int pc = (scnt[e] + 127) & ~127;
      for (int i = 0; i < pc / 128; i++) {
        meta->tile_e[nt] = e; meta->tile_m0[nt] = po + i * 128; nt++;
      }
      po += pc;
    }
    meta->pad_off[NE] = po;
    meta->n_mtiles = nt;
    aux_out[0] = aux * (8.f / ((float)T_TOK * (float)T_TOK));
  }
}

// -------- deterministic scatter: one wave per expert, ballot-scan ----------
__global__ __launch_bounds__(64) void scatter_kernel(
    const int* __restrict__ topi, const float* __restrict__ topw,
    const Meta* __restrict__ meta,
    int* __restrict__ t_of, float* __restrict__ w_of, int* __restrict__ k_of) {
  int e = blockIdx.x, lane = threadIdx.x;
  int base = meta->pad_off[e];
  for (int c = 0; c < T_TOK * 2; c += 64) {
    int idx = c + lane;
    int sel = (topi[idx] == e) ? 1 : 0;
    unsigned long long mask = __ballot(sel);
    if (sel) {
      int rank = __popcll(mask & ((1ull << lane) - 1ull));
      int s = base + rank;
      t_of[s] = idx >> 1;
      k_of[s] = idx & 1;
      w_of[s] = topw[idx];
    }
    base += (int)__popcll(mask);
  }
}

// -------- gather tokens into bucket order, fp32 -> bf16 --------------------
__global__ __launch_bounds__(256) void gather_kernel(
    const float* __restrict__ x, const int* __restrict__ t_of,
    unsigned short* __restrict__ Xg_u) {
  int s = blockIdx.x;
  int t = t_of[s];
  if (t < 0) return;  // pad / unused slot
  bf16* Xg = (bf16*)Xg_u;
  int i = threadIdx.x;
  float4 v = ((const float4*)(x + (size_t)t * DM))[i];
  bf16x4 o = {(bf16)v.x, (bf16)v.y, (bf16)v.z, (bf16)v.w};
  ((bf16x4*)(Xg + (size_t)s * DM))[i] = o;
}

// -------- transpose-convert weights: src fp32 [E][R][C] -> dst bf16 [E][C][R]
__global__ __launch_bounds__(256) void transpose_kernel(
    const float* __restrict__ src, unsigned short* __restrict__ dst_u, int R, int C) {
  bf16* dst = (bf16*)dst_u;
  int e = blockIdx.z;
  int c0 = blockIdx.x * 32, r0 = blockIdx.y * 32;
  int tx = threadIdx.x & 31, ty = threadIdx.x >> 5;  // ty: 0..7
  __shared__ float tile[32][33];
  const float* s = src + (size_t)e * R * C;
#pragma unroll
  for (int j = 0; j < 32; j += 8)
    tile[ty + j][tx] = s[(size_t)(r0 + ty + j) * C + c0 + tx];
  __syncthreads();
  bf16* d = dst + (size_t)e * C * R;
#pragma unroll
  for (int j = 0; j < 32; j += 8)
    d[(size_t)(c0 + ty + j) * R + r0 + tx] = (bf16)tile[tx][ty + j];
}

// -------- async global -> LDS, 16B per lane --------------------------------
__device__ inline void gl_lds16(const void* g, void* l) {
  __builtin_amdgcn_global_load_lds(
      (const __attribute__((address_space(1))) unsigned int*)g,
      (__attribute__((address_space(3))) unsigned int*)l, 16, 0, 0);
}

// -------- grouped GEMM: C[128x128] per block, A [M][K] bf16, Bt [E][N][K] bf16
// MODE 1: h = relu(acc + b1) -> bf16 Hbuf (ld = N = DF)
// MODE 2: y = (acc + b2) * gate -> fp32 Yslots[k][t][DM]
template <int MODE>
__global__ __launch_bounds__(256) void gemm_kernel(
    const unsigned short* __restrict__ A_u, const unsigned short* __restrict__ Bt_u,
    const float* __restrict__ bias, const Meta* __restrict__ meta,
    int K, int N,
    unsigned short* __restrict__ Hout_u, float* __restrict__ Yout,
    const int* __restrict__ t_of, const int* __restrict__ k_of,
    const float* __restrict__ w_of) {
  int bx = blockIdx.x;
  if (bx >= meta->n_mtiles) return;
  const bf16* A = (const bf16*)A_u;
  const bf16* Bt = (const bf16*)Bt_u;
  int e = meta->tile_e[bx];
  int m0 = meta->tile_m0[bx];
  int n0 = blockIdx.y * 128;
  const bf16* Be = Bt + (size_t)e * N * K;

  __shared__ bf16 As[128 * 64];  // [row][k] row stride 64
  __shared__ bf16 Bs[128 * 64];  // [n][k]   row stride 64

  int tid = threadIdx.x, lane = tid & 63, wave = tid >> 6;
  int wr = wave >> 1, wc = wave & 1;       // 2x2 wave grid, 64x64 each
  int srow = lane >> 3;                    // staging: 8 rows per wave chunk
  int scol = (lane & 7) * 8;               // 8 bf16 = 16B per lane

  const bf16* Ag = A + (size_t)(m0 + wave * 8 + srow) * K + scol;
  const bf16* Bg = Be + (size_t)(n0 + wave * 8 + srow) * K + scol;
  bf16* AsW = As + wave * 512;             // wave-uniform LDS base (bytes: wave*1024)
  bf16* BsW = Bs + wave * 512;

  f32x4 acc[4][4];
#pragma unroll
  for (int i = 0; i < 4; i++)
#pragma unroll
    for (int j = 0; j < 4; j++) acc[i][j] = (f32x4){0.f, 0.f, 0.f, 0.f};

  int fr = lane & 15;          // A row / B col within 16x16 tile
  int kq = (lane >> 4) * 8;    // k-group base

  for (int k0 = 0; k0 < K; k0 += 64) {
#pragma unroll
    for (int r = 0; r < 4; r++) {
      gl_lds16(Ag + (size_t)(r * 32) * K + k0, AsW + r * 2048);
      gl_lds16(Bg + (size_t)(r * 32) * K + k0, BsW + r * 2048);
    }
    __syncthreads();  // compiler emits vmcnt(0) drain before s_barrier
#pragma unroll
    for (int kk = 0; kk < 64; kk += 32) {
      bf16x8 af[4], bfr[4];
#pragma unroll
      for (int i = 0; i < 4; i++)
        af[i] = *(const bf16x8*)&As[(wr * 64 + i * 16 + fr) * 64 + kk + kq];
#pragma unroll
      for (int j = 0; j < 4; j++)
        bfr[j] = *(const bf16x8*)&Bs[(wc * 64 + j * 16 + fr) * 64 + kk + kq];
#pragma unroll
      for (int i = 0; i < 4; i++)
#pragma unroll
        for (int j = 0; j < 4; j++)
          acc[i][j] = __builtin_amdgcn_mfma_f32_16x16x32_bf16(af[i], bfr[j], acc[i][j], 0, 0, 0);
    }
    __syncthreads();
  }

  // epilogue; C/D layout: col = lane&15, row = (lane>>4)*4 + reg  [m89/m91]
  int crow = (lane >> 4) * 4;
  int ccol = lane & 15;
  if (MODE == 1) {
    bf16* Hout = (bf16*)Hout_u;
#pragma unroll
    for (int i = 0; i < 4; i++) {
#pragma unroll
      for (int r = 0; r < 4; r++) {
        int slot = m0 + wr * 64 + i * 16 + crow + r;
        bf16* hrow = Hout + (size_t)slot * N;
#pragma unroll
        for (int j = 0; j < 4; j++) {
          int n = n0 + wc * 64 + j * 16 + ccol;
          float v = acc[i][j][r] + bias[e * N + n];
          hrow[n] = (bf16)fmaxf(v, 0.f);
        }
      }
    }
  } else {
#pragma unroll
    for (int i = 0; i < 4; i++) {
#pragma unroll
      for (int r = 0; r < 4; r++) {
        int slot = m0 + wr * 64 + i * 16 + crow + r;
        int t = t_of[slot];
        if (t < 0) continue;  // padding row
        int ks = k_of[slot];
        float w = w_of[slot];
        float* yrow = Yout + ((size_t)ks * T_TOK + t) * DM;
#pragma unroll
        for (int j = 0; j < 4; j++) {
          int n = n0 + wc * 64 + j * 16 + ccol;
          yrow[n] = (acc[i][j][r] + bias[e * DM + n]) * w;
        }
      }
    }
  }
}

// -------- residual + LayerNorm --------------------------------------------
__global__ __launch_bounds__(256) void ln_kernel(
    const float* __restrict__ x, const float* __restrict__ Ysl,
    const float* __restrict__ gamma, const float* __restrict__ beta,
    float* __restrict__ out) {
  int t = blockIdx.x, tid = threadIdx.x, lane = tid & 63, wave = tid >> 6;
  float4 a = ((const float4*)(x + (size_t)t * DM))[tid];
  float4 y0 = ((const float4*)(Ysl + (size_t)t * DM))[tid];
  float4 y1 = ((const float4*)(Ysl + ((size_t)T_TOK + t) * DM))[tid];
  float4 sv;
  sv.x = a.x + y0.x + y1.x; sv.y = a.y + y0.y + y1.y;
  sv.z = a.z + y0.z + y1.z; sv.w = a.w + y0.w + y1.w;
  float sum = sv.x + sv.y + sv.z + sv.w;
  float sq = sv.x * sv.x + sv.y * sv.y + sv.z * sv.z + sv.w * sv.w;
#pragma unroll
  for (int off = 32; off >= 1; off >>= 1) {
    sum += __shfl_xor(sum, off);
    sq += __shfl_xor(sq, off);
  }
  __shared__ float ls[4], lq[4], stats[2];
  if (lane == 0) { ls[wave] = sum; lq[wave] = sq; }
  __syncthreads();
  if (tid == 0) {
    float ts = ls[0] + ls[1] + ls[2] + ls[3];
    float tq = lq[0] + lq[1] + lq[2] + lq[3];
    float mu = ts * (1.f / DM);
    float var = tq * (1.f / DM) - mu * mu;
    stats[0] = mu;
    stats[1] = rsqrtf(var + 1e-5f);
  }
  __syncthreads();
  float mu = stats[0], rs = stats[1];
  float4 g = ((const float4*)gamma)[tid];
  float4 b = ((const float4*)beta)[tid];
  float4 o;
  o.x = (sv.x - mu) * rs * g.x + b.x;
  o.y = (sv.y - mu) * rs * g.y + b.y;
  o.z = (sv.z - mu) * rs * g.z + b.z;
  o.w = (sv.w - mu) * rs * g.w + b.w;
  ((float4*)(out + (size_t)t * DM))[tid] = o;
}

// ---------------------------------------------------------------------------
extern "C" void kernel_launch(void* const* d_in, const int* in_sizes, int n_in,
                              void* d_out, int out_size, void* d_ws, size_t ws_size,
                              hipStream_t stream) {
  const float* x     = (const float*)d_in[0];
  // d_in[1] = mask (all ones, unused by reference math)
  const float* Wg    = (const float*)d_in[2];
  const float* W1    = (const float*)d_in[3];
  const float* b1    = (const float*)d_in[4];
  const float* W2    = (const float*)d_in[5];
  const float* b2    = (const float*)d_in[6];
  const float* gamma = (const float*)d_in[7];
  const float* beta  = (const float*)d_in[8];
  float* out = (float*)d_out;

  char* ws = (char*)d_ws;
  size_t off = 0;
  auto alloc = [&](size_t bytes) -> void* {
    off = (off + 4095) & ~(size_t)4095;
    void* p = ws + off;
    off += bytes;
    return p;
  };
  Meta* meta   = (Meta*)alloc(sizeof(Meta));
  int* topi    = (int*)alloc((size_t)T_TOK * 2 * 4);
  float* topw  = (float*)alloc((size_t)T_TOK * 2 * 4);
  float* probs = (float*)alloc((size_t)T_TOK * NE * 4);
  int* t_of    = (int*)alloc((size_t)CAP * 4);
  int* k_of    = (int*)alloc((size_t)CAP * 4);
  float* w_of  = (float*)alloc((size_t)CAP * 4);
  unsigned short* Xg   = (unsigned short*)alloc((size_t)CAP * DM * 2);   // 18.9 MB
  unsigned short* Hbuf = (unsigned short*)alloc((size_t)CAP * DF * 2);   // 75.5 MB
  float* Ysl           = (float*)alloc((size_t)2 * T_TOK * DM * 4);      // 33.6 MB
  unsigned short* WT   = (unsigned short*)alloc((size_t)NE * DM * DF * 2); // 67.1 MB, W1T then W2T

  // mark all slots as padding; scatter fills real ones
  hipMemsetAsync(t_of, 0xFF, (size_t)CAP * 4, stream);

  router_kernel<<<dim3(T_TOK / 4), dim3(256), 0, stream>>>(x, Wg, topi, topw, probs);
  prep_kernel<<<dim3(1), dim3(256), 0, stream>>>(topi, probs, meta, out + (size_t)T_TOK * DM);
  scatter_kernel<<<dim3(NE), dim3(64), 0, stream>>>(topi, topw, meta, t_of, w_of, k_of);
  gather_kernel<<<dim3(CAP), dim3(256), 0, stream>>>(x, t_of, Xg);

  // W1 [E][DM][DF] -> W1T [E][DF][DM] (bf16, k-contiguous)
  transpose_kernel<<<dim3(DF / 32, DM / 32, NE), dim3(256), 0, stream>>>(W1, WT, DM, DF);
  gemm_kernel<1><<<dim3(MAXMT, DF / 128), dim3(256), 0, stream>>>(
      Xg, WT, b1, meta, DM, DF, Hbuf, (float*)nullptr,
      (const int*)nullptr, (const int*)nullptr, (const float*)nullptr);

  // W2 [E][DF][DM] -> W2T [E][DM][DF] (reuses WT buffer after GEMM1)
  transpose_kernel<<<dim3(DM / 32, DF / 32, NE), dim3(256), 0, stream>>>(W2, WT, DF, DM);
  gemm_kernel<2><<<dim3(MAXMT, DM / 128), dim3(256), 0, stream>>>(
      Hbuf, WT, b2, meta, DF, DM, (unsigned short*)nullptr, Ysl, t_of, k_of, w_of);

  ln_kernel<<<dim3(T_TOK), dim3(256), 0, stream>>>(x, Ysl, gamma, beta, out);
}

// Round 2
// 674.552 us; speedup vs baseline: 1.1134x; 1.1134x over previous
//
#include <hip/hip_runtime.h>
#include <cstdint>
#include <cstddef>

// ---------------------------------------------------------------------------
// MoE encoder layer: x[4,1024,1024] fp32, top-2 of 8 experts, D=1024, F=4096.
// R2: split-K=2 GEMM2 (occupancy 2->4.5 blk/CU), XOR granule swizzle in LDS
// (kills 16-lane bank-quad conflicts on ds_read_b128), bf16x2 transpose stores.
// Partials: P[z][kslot][T][DM] fp32; P(z=1) reuses the dead Xg region.
// ---------------------------------------------------------------------------

#define T_TOK 4096
#define DM 1024
#define DF 4096
#define NE 8
#define CAP 9216      // 8192 slots + 8*128 padding headroom
#define MAXMT 72      // max 128-row M-tiles: 64 + 8

typedef __bf16 bf16;
typedef __bf16 bf16x2 __attribute__((ext_vector_type(2)));
typedef __bf16 bf16x4 __attribute__((ext_vector_type(4)));
typedef __bf16 bf16x8 __attribute__((ext_vector_type(8)));
typedef float f32x4 __attribute__((ext_vector_type(4)));

struct Meta {
  int pad_off[NE + 1];
  int n_mtiles;
  int tile_e[80];
  int tile_m0[80];
};

// ---------------- router: logits, softmax probs, top-2 ---------------------
__global__ __launch_bounds__(256) void router_kernel(
    const float* __restrict__ x, const float* __restrict__ Wg,
    int* __restrict__ topi, float* __restrict__ topw, float* __restrict__ probs) {
  int wave = threadIdx.x >> 6, lane = threadIdx.x & 63;
  int t = blockIdx.x * 4 + wave;
  const float* xr = x + (size_t)t * DM;
  float acc[NE];
#pragma unroll
  for (int e = 0; e < NE; e++) acc[e] = 0.f;
  for (int d0 = 0; d0 < DM; d0 += 64) {
    float xv = xr[d0 + lane];
    const float4* wrow = (const float4*)(Wg + (size_t)(d0 + lane) * NE);
    float4 w0 = wrow[0], w1 = wrow[1];
    acc[0] += xv * w0.x; acc[1] += xv * w0.y; acc[2] += xv * w0.z; acc[3] += xv * w0.w;
    acc[4] += xv * w1.x; acc[5] += xv * w1.y; acc[6] += xv * w1.z; acc[7] += xv * w1.w;
  }
#pragma unroll
  for (int off = 32; off >= 1; off >>= 1) {
#pragma unroll
    for (int e = 0; e < NE; e++) acc[e] += __shfl_xor(acc[e], off);
  }
  if (lane == 0) {
    float m = acc[0];
#pragma unroll
    for (int e = 1; e < NE; e++) m = fmaxf(m, acc[e]);
    float p[NE], s = 0.f;
#pragma unroll
    for (int e = 0; e < NE; e++) { p[e] = expf(acc[e] - m); s += p[e]; }
    float inv = 1.f / s;
#pragma unroll
    for (int e = 0; e < NE; e++) { p[e] *= inv; probs[t * NE + e] = p[e]; }
    int i1 = 0; float v1 = acc[0];
#pragma unroll
    for (int e = 1; e < NE; e++) if (acc[e] > v1) { v1 = acc[e]; i1 = e; }
    int i2 = -1; float v2 = -1e30f;
#pragma unroll
    for (int e = 0; e < NE; e++) if (e != i1 && acc[e] > v2) { v2 = acc[e]; i2 = e; }
    float sw = p[i1] + p[i2];
    topi[t * 2] = i1; topi[t * 2 + 1] = i2;
    topw[t * 2] = p[i1] / sw; topw[t * 2 + 1] = p[i2] / sw;
  }
}

// -------- prep: counts, aux loss, padded offsets, M-tile table (1 block) ----
__global__ __launch_bounds__(256) void prep_kernel(
    const int* __restrict__ topi, const float* __restrict__ probs,
    Meta* __restrict__ meta, float* __restrict__ aux_out) {
  __shared__ int scnt[NE];
  __shared__ float wps[4][NE];
  int tid = threadIdx.x, lane = tid & 63, wave = tid >> 6;
  if (tid < NE) scnt[tid] = 0;
  __syncthreads();
  for (int i = tid; i < T_TOK * 2; i += 256) atomicAdd(&scnt[topi[i]], 1);
  float lp[NE];
#pragma unroll
  for (int e = 0; e < NE; e++) lp[e] = 0.f;
  for (int tt = tid; tt < T_TOK; tt += 256) {
#pragma unroll
    for (int e = 0; e < NE; e++) lp[e] += probs[tt * NE + e];
  }
#pragma unroll
  for (int off = 32; off >= 1; off >>= 1) {
#pragma unroll
    for (int e = 0; e < NE; e++) lp[e] += __shfl_xor(lp[e], off);
  }
  if (lane == 0) {
#pragma unroll
    for (int e = 0; e < NE; e++) wps[wave][e] = lp[e];
  }
  __syncthreads();
  if (tid == 0) {
    float aux = 0.f;
    int nt = 0, po = 0;
    for (int e = 0; e < NE; e++) {
      float ps = wps[0][e] + wps[1][e] + wps[2][e] + wps[3][e];
      aux += (float)scnt[e] * ps;
      meta->pad_off[e] = po;
      int pc = (scnt[e] + 127) & ~127;
      for (int i = 0; i < pc / 128; i++) {
        meta->tile_e[nt] = e; meta->tile_m0[nt] = po + i * 128; nt++;
      }
      po += pc;
    }
    meta->pad_off[NE] = po;
    meta->n_mtiles = nt;
    aux_out[0] = aux * (8.f / ((float)T_TOK * (float)T_TOK));
  }
}

// -------- deterministic scatter: one wave per expert, ballot-scan ----------
__global__ __launch_bounds__(64) void scatter_kernel(
    const int* __restrict__ topi, const float* __restrict__ topw,
    const Meta* __restrict__ meta,
    int* __restrict__ t_of, float* __restrict__ w_of, int* __restrict__ k_of) {
  int e = blockIdx.x, lane = threadIdx.x;
  int base = meta->pad_off[e];
  for (int c = 0; c < T_TOK * 2; c += 64) {
    int idx = c + lane;
    int sel = (topi[idx] == e) ? 1 : 0;
    unsigned long long mask = __ballot(sel);
    if (sel) {
      int rank = __popcll(mask & ((1ull << lane) - 1ull));
      int s = base + rank;
      t_of[s] = idx >> 1;
      k_of[s] = idx & 1;
      w_of[s] = topw[idx];
    }
    base += (int)__popcll(mask);
  }
}

// -------- gather tokens into bucket order, fp32 -> bf16 --------------------
__global__ __launch_bounds__(256) void gather_kernel(
    const float* __restrict__ x, const int* __restrict__ t_of,
    unsigned short* __restrict__ Xg_u) {
  int s = blockIdx.x;
  int t = t_of[s];
  if (t < 0) return;
  bf16* Xg = (bf16*)Xg_u;
  int i = threadIdx.x;
  float4 v = ((const float4*)(x + (size_t)t * DM))[i];
  bf16x4 o = {(bf16)v.x, (bf16)v.y, (bf16)v.z, (bf16)v.w};
  ((bf16x4*)(Xg + (size_t)s * DM))[i] = o;
}

// -------- transpose-convert weights: src fp32 [E][R][C] -> dst bf16 [E][C][R]
__global__ __launch_bounds__(256) void transpose_kernel(
    const float* __restrict__ src, unsigned short* __restrict__ dst_u, int R, int C) {
  bf16* dst = (bf16*)dst_u;
  int e = blockIdx.z;
  int c0 = blockIdx.x * 32, r0 = blockIdx.y * 32;
  int tx = threadIdx.x & 31, ty = threadIdx.x >> 5;
  __shared__ float tile[32][33];
  const float* s = src + (size_t)e * R * C;
#pragma unroll
  for (int j = 0; j < 32; j += 8)
    tile[ty + j][tx] = s[(size_t)(r0 + ty + j) * C + c0 + tx];
  __syncthreads();
  bf16* d = dst + (size_t)e * C * R;
  int wr_ = threadIdx.x & 15;        // row-pair
  int wc_ = threadIdx.x >> 4;        // col 0..15
#pragma unroll
  for (int j = 0; j < 32; j += 16) {
    int c = wc_ + j;
    bf16x2 v = {(bf16)tile[2 * wr_][c], (bf16)tile[2 * wr_ + 1][c]};
    *(bf16x2*)&d[(size_t)(c0 + c) * R + r0 + 2 * wr_] = v;
  }
}

// -------- async global -> LDS, 16B per lane --------------------------------
__device__ inline void gl_lds16(const void* g, void* l) {
  __builtin_amdgcn_global_load_lds(
      (const __attribute__((address_space(1))) unsigned int*)g,
      (__attribute__((address_space(3))) unsigned int*)l, 16, 0, 0);
}

// -------- grouped GEMM, 128x128 tile, BK=64, swizzled LDS ------------------
// MODE 1: h = relu(acc + b1) -> bf16 Hout
// MODE 2: y = (acc + (z==0 ? b2 : 0)) * gate -> fp32 Pz[kslot][t][DM]
//         (P0 for blockIdx.z==0, P1 for blockIdx.z==1; race-free by (z,kslot))
template <int MODE>
__global__ __launch_bounds__(256) void gemm_kernel(
    const unsigned short* __restrict__ A_u, const unsigned short* __restrict__ Bt_u,
    const float* __restrict__ bias, const Meta* __restrict__ meta,
    int Ktot, int Ksp, int N,
    unsigned short* __restrict__ Hout_u,
    float* __restrict__ P0, float* __restrict__ P1,
    const int* __restrict__ t_of, const int* __restrict__ k_of,
    const float* __restrict__ w_of) {
  int bx = blockIdx.x;
  if (bx >= meta->n_mtiles) return;
  const bf16* A = (const bf16*)A_u;
  const bf16* Bt = (const bf16*)Bt_u;
  int e = meta->tile_e[bx];
  int m0 = meta->tile_m0[bx];
  int n0 = blockIdx.y * 128;
  int koff = blockIdx.z * Ksp;
  const bf16* Be = Bt + (size_t)e * N * Ktot;

  __shared__ bf16 As[128 * 64];  // [row][k], granule-swizzled: p holds g = p^(row&7)
  __shared__ bf16 Bs[128 * 64];

  int tid = threadIdx.x, lane = tid & 63, wave = tid >> 6;
  int wr = wave >> 1, wc = wave & 1;
  int srow = lane >> 3;
  int sgran = lane & 7;
  int gcol = (sgran ^ srow) * 8;           // swizzled source column (elements)

  const bf16* Ag = A + (size_t)(m0 + wave * 8 + srow) * Ktot + koff + gcol;
  const bf16* Bg = Be + (size_t)(n0 + wave * 8 + srow) * Ktot + koff + gcol;
  bf16* AsW = As + wave * 512;
  bf16* BsW = Bs + wave * 512;

  f32x4 acc[4][4];
#pragma unroll
  for (int i = 0; i < 4; i++)
#pragma unroll
    for (int j = 0; j < 4; j++) acc[i][j] = (f32x4){0.f, 0.f, 0.f, 0.f};

  int fr = lane & 15;
  int qh = lane >> 4;
  int swz = fr & 7;

  for (int k0 = 0; k0 < Ksp; k0 += 64) {
#pragma unroll
    for (int r = 0; r < 4; r++) {
      gl_lds16(Ag + (size_t)(r * 32) * Ktot + k0, AsW + r * 2048);
      gl_lds16(Bg + (size_t)(r * 32) * Ktot + k0, BsW + r * 2048);
    }
    __syncthreads();
#pragma unroll
    for (int kk = 0; kk < 64; kk += 32) {
      int col = (((kk >> 3) | qh) ^ swz) * 8;
      bf16x8 af[4], bfr[4];
#pragma unroll
      for (int i = 0; i < 4; i++)
        af[i] = *(const bf16x8*)&As[(wr * 64 + i * 16 + fr) * 64 + col];
#pragma unroll
      for (int j = 0; j < 4; j++)
        bfr[j] = *(const bf16x8*)&Bs[(wc * 64 + j * 16 + fr) * 64 + col];
#pragma unroll
      for (int i = 0; i < 4; i++)
#pragma unroll
        for (int j = 0; j < 4; j++)
          acc[i][j] = __builtin_amdgcn_mfma_f32_16x16x32_bf16(af[i], bfr[j], acc[i][j], 0, 0, 0);
    }
    __syncthreads();
  }

  // epilogue; C/D layout: col = lane&15, row = (lane>>4)*4 + reg  [m89/m91]
  int crow = (lane >> 4) * 4;
  int ccol = lane & 15;
  if (MODE == 1) {
    bf16* Hout = (bf16*)Hout_u;
#pragma unroll
    for (int i = 0; i < 4; i++) {
#pragma unroll
      for (int r = 0; r < 4; r++) {
        int slot = m0 + wr * 64 + i * 16 + crow + r;
        bf16* hrow = Hout + (size_t)slot * N;
#pragma unroll
        for (int j = 0; j < 4; j++) {
          int n = n0 + wc * 64 + j * 16 + ccol;
          float v = acc[i][j][r] + bias[e * N + n];
          hrow[n] = (bf16)fmaxf(v, 0.f);
        }
      }
    }
  } else {
    float* Pz = (blockIdx.z == 0) ? P0 : P1;
    int addb = (blockIdx.z == 0) ? 1 : 0;
#pragma unroll
    for (int i = 0; i < 4; i++) {
#pragma unroll
      for (int r = 0; r < 4; r++) {
        int slot = m0 + wr * 64 + i * 16 + crow + r;
        int t = t_of[slot];
        if (t < 0) continue;
        int ks = k_of[slot];
        float w = w_of[slot];
        float* yrow = Pz + ((size_t)ks * T_TOK + t) * DM;
#pragma unroll
        for (int j = 0; j < 4; j++) {
          int n = n0 + wc * 64 + j * 16 + ccol;
          float bv = addb ? bias[e * DM + n] : 0.f;
          yrow[n] = (acc[i][j][r] + bv) * w;
        }
      }
    }
  }
}

// -------- residual + LayerNorm (sums 4 split-K partials) -------------------
__global__ __launch_bounds__(256) void ln_kernel(
    const float* __restrict__ x,
    const float* __restrict__ P0, const float* __restrict__ P1,
    const float* __restrict__ gamma, const float* __restrict__ beta,
    float* __restrict__ out) {
  int t = blockIdx.x, tid = threadIdx.x, lane = tid & 63, wave = tid >> 6;
  size_t row = (size_t)t * DM;
  size_t kstride = (size_t)T_TOK * DM;
  float4 a  = ((const float4*)(x + row))[tid];
  float4 y0 = ((const float4*)(P0 + row))[tid];
  float4 y1 = ((const float4*)(P0 + kstride + row))[tid];
  float4 y2 = ((const float4*)(P1 + row))[tid];
  float4 y3 = ((const float4*)(P1 + kstride + row))[tid];
  float4 sv;
  sv.x = a.x + y0.x + y1.x + y2.x + y3.x;
  sv.y = a.y + y0.y + y1.y + y2.y + y3.y;
  sv.z = a.z + y0.z + y1.z + y2.z + y3.z;
  sv.w = a.w + y0.w + y1.w + y2.w + y3.w;
  float sum = sv.x + sv.y + sv.z + sv.w;
  float sq = sv.x * sv.x + sv.y * sv.y + sv.z * sv.z + sv.w * sv.w;
#pragma unroll
  for (int off = 32; off >= 1; off >>= 1) {
    sum += __shfl_xor(sum, off);
    sq += __shfl_xor(sq, off);
  }
  __shared__ float ls[4], lq[4], stats[2];
  if (lane == 0) { ls[wave] = sum; lq[wave] = sq; }
  __syncthreads();
  if (tid == 0) {
    float ts = ls[0] + ls[1] + ls[2] + ls[3];
    float tq = lq[0] + lq[1] + lq[2] + lq[3];
    float mu = ts * (1.f / DM);
    float var = tq * (1.f / DM) - mu * mu;
    stats[0] = mu;
    stats[1] = rsqrtf(var + 1e-5f);
  }
  __syncthreads();
  float mu = stats[0], rs = stats[1];
  float4 g = ((const float4*)gamma)[tid];
  float4 b = ((const float4*)beta)[tid];
  float4 o;
  o.x = (sv.x - mu) * rs * g.x + b.x;
  o.y = (sv.y - mu) * rs * g.y + b.y;
  o.z = (sv.z - mu) * rs * g.z + b.z;
  o.w = (sv.w - mu) * rs * g.w + b.w;
  ((float4*)(out + row))[tid] = o;
}

// ---------------------------------------------------------------------------
extern "C" void kernel_launch(void* const* d_in, const int* in_sizes, int n_in,
                              void* d_out, int out_size, void* d_ws, size_t ws_size,
                              hipStream_t stream) {
  const float* x     = (const float*)d_in[0];
  const float* Wg    = (const float*)d_in[2];
  const float* W1    = (const float*)d_in[3];
  const float* b1    = (const float*)d_in[4];
  const float* W2    = (const float*)d_in[5];
  const float* b2    = (const float*)d_in[6];
  const float* gamma = (const float*)d_in[7];
  const float* beta  = (const float*)d_in[8];
  float* out = (float*)d_out;

  char* ws = (char*)d_ws;
  size_t off = 0;
  auto alloc = [&](size_t bytes) -> void* {
    off = (off + 4095) & ~(size_t)4095;
    void* p = ws + off;
    off += bytes;
    return p;
  };
  Meta* meta   = (Meta*)alloc(sizeof(Meta));
  int* topi    = (int*)alloc((size_t)T_TOK * 2 * 4);
  float* topw  = (float*)alloc((size_t)T_TOK * 2 * 4);
  float* probs = (float*)alloc((size_t)T_TOK * NE * 4);
  int* t_of    = (int*)alloc((size_t)CAP * 4);
  int* k_of    = (int*)alloc((size_t)CAP * 4);
  float* w_of  = (float*)alloc((size_t)CAP * 4);
  // Xg (18.9 MB) is dead after gemm1; its region doubles as split-1 partials
  size_t xg_bytes = (size_t)CAP * DM * 2;
  size_t p_bytes  = (size_t)2 * T_TOK * DM * 4;           // 33.6 MB
  char* xg_region = (char*)alloc(xg_bytes > p_bytes ? xg_bytes : p_bytes);
  unsigned short* Xg = (unsigned short*)xg_region;
  float* Psp1        = (float*)xg_region;
  unsigned short* Hbuf = (unsigned short*)alloc((size_t)CAP * DF * 2);    // 75.5 MB
  float* Psp0          = (float*)alloc(p_bytes);                           // 33.6 MB
  unsigned short* WT   = (unsigned short*)alloc((size_t)NE * DM * DF * 2); // 67.1 MB

  hipMemsetAsync(t_of, 0xFF, (size_t)CAP * 4, stream);

  router_kernel<<<dim3(T_TOK / 4), dim3(256), 0, stream>>>(x, Wg, topi, topw, probs);
  prep_kernel<<<dim3(1), dim3(256), 0, stream>>>(topi, probs, meta, out + (size_t)T_TOK * DM);
  scatter_kernel<<<dim3(NE), dim3(64), 0, stream>>>(topi, topw, meta, t_of, w_of, k_of);
  gather_kernel<<<dim3(CAP), dim3(256), 0, stream>>>(x, t_of, Xg);

  transpose_kernel<<<dim3(DF / 32, DM / 32, NE), dim3(256), 0, stream>>>(W1, WT, DM, DF);
  gemm_kernel<1><<<dim3(MAXMT, DF / 128, 1), dim3(256), 0, stream>>>(
      Xg, WT, b1, meta, DM, DM, DF, Hbuf, (float*)nullptr, (float*)nullptr,
      (const int*)nullptr, (const int*)nullptr, (const float*)nullptr);

  transpose_kernel<<<dim3(DM / 32, DF / 32, NE), dim3(256), 0, stream>>>(W2, WT, DF, DM);
  gemm_kernel<2><<<dim3(MAXMT, DM / 128, 2), dim3(256), 0, stream>>>(
      Hbuf, WT, b2, meta, DF, DF / 2, DM, (unsigned short*)nullptr, Psp0, Psp1,
      t_of, k_of, w_of);

  ln_kernel<<<dim3(T_TOK), dim3(256), 0, stream>>>(x, Psp0, Psp1, gamma, beta, out);
}

// Round 3
// 643.410 us; speedup vs baseline: 1.1673x; 1.0484x over previous
//
#include <hip/hip_runtime.h>
#include <cstdint>
#include <cstddef>

// ---------------------------------------------------------------------------
// MoE encoder layer: x[4,1024,1024] fp32, top-2 of 8 experts, D=1024, F=4096.
// R3: XCD-aware block swizzle in both GEMMs (expert-aligned bx slabs per XCD,
// FETCH over-fetch 328->~170MB), fast 64x64 transpose (float4 loads, bf16x8
// stores). R2's LDS granule swizzle (0 bank conflicts) and split-K=2 retained.
// ---------------------------------------------------------------------------

#define T_TOK 4096
#define DM 1024
#define DF 4096
#define NE 8
#define CAP 9216      // 8192 slots + 8*128 padding headroom
#define MAXMT 72      // max 128-row M-tiles: 64 + 8 (divisible by 8 for swizzle)

typedef __bf16 bf16;
typedef __bf16 bf16x4 __attribute__((ext_vector_type(4)));
typedef __bf16 bf16x8 __attribute__((ext_vector_type(8)));
typedef float f32x4 __attribute__((ext_vector_type(4)));

struct Meta {
  int pad_off[NE + 1];
  int n_mtiles;
  int tile_e[80];
  int tile_m0[80];
};

// ---------------- router: logits, softmax probs, top-2 ---------------------
__global__ __launch_bounds__(256) void router_kernel(
    const float* __restrict__ x, const float* __restrict__ Wg,
    int* __restrict__ topi, float* __restrict__ topw, float* __restrict__ probs) {
  int wave = threadIdx.x >> 6, lane = threadIdx.x & 63;
  int t = blockIdx.x * 4 + wave;
  const float* xr = x + (size_t)t * DM;
  float acc[NE];
#pragma unroll
  for (int e = 0; e < NE; e++) acc[e] = 0.f;
  for (int d0 = 0; d0 < DM; d0 += 64) {
    float xv = xr[d0 + lane];
    const float4* wrow = (const float4*)(Wg + (size_t)(d0 + lane) * NE);
    float4 w0 = wrow[0], w1 = wrow[1];
    acc[0] += xv * w0.x; acc[1] += xv * w0.y; acc[2] += xv * w0.z; acc[3] += xv * w0.w;
    acc[4] += xv * w1.x; acc[5] += xv * w1.y; acc[6] += xv * w1.z; acc[7] += xv * w1.w;
  }
#pragma unroll
  for (int off = 32; off >= 1; off >>= 1) {
#pragma unroll
    for (int e = 0; e < NE; e++) acc[e] += __shfl_xor(acc[e], off);
  }
  if (lane == 0) {
    float m = acc[0];
#pragma unroll
    for (int e = 1; e < NE; e++) m = fmaxf(m, acc[e]);
    float p[NE], s = 0.f;
#pragma unroll
    for (int e = 0; e < NE; e++) { p[e] = expf(acc[e] - m); s += p[e]; }
    float inv = 1.f / s;
#pragma unroll
    for (int e = 0; e < NE; e++) { p[e] *= inv; probs[t * NE + e] = p[e]; }
    int i1 = 0; float v1 = acc[0];
#pragma unroll
    for (int e = 1; e < NE; e++) if (acc[e] > v1) { v1 = acc[e]; i1 = e; }
    int i2 = -1; float v2 = -1e30f;
#pragma unroll
    for (int e = 0; e < NE; e++) if (e != i1 && acc[e] > v2) { v2 = acc[e]; i2 = e; }
    float sw = p[i1] + p[i2];
    topi[t * 2] = i1; topi[t * 2 + 1] = i2;
    topw[t * 2] = p[i1] / sw; topw[t * 2 + 1] = p[i2] / sw;
  }
}

// -------- prep: counts, aux loss, padded offsets, M-tile table (1 block) ----
__global__ __launch_bounds__(256) void prep_kernel(
    const int* __restrict__ topi, const float* __restrict__ probs,
    Meta* __restrict__ meta, float* __restrict__ aux_out) {
  __shared__ int scnt[NE];
  __shared__ float wps[4][NE];
  int tid = threadIdx.x, lane = tid & 63, wave = tid >> 6;
  if (tid < NE) scnt[tid] = 0;
  __syncthreads();
  for (int i = tid; i < T_TOK * 2; i += 256) atomicAdd(&scnt[topi[i]], 1);
  float lp[NE];
#pragma unroll
  for (int e = 0; e < NE; e++) lp[e] = 0.f;
  for (int tt = tid; tt < T_TOK; tt += 256) {
#pragma unroll
    for (int e = 0; e < NE; e++) lp[e] += probs[tt * NE + e];
  }
#pragma unroll
  for (int off = 32; off >= 1; off >>= 1) {
#pragma unroll
    for (int e = 0; e < NE; e++) lp[e] += __shfl_xor(lp[e], off);
  }
  if (lane == 0) {
#pragma unroll
    for (int e = 0; e < NE; e++) wps[wave][e] = lp[e];
  }
  __syncthreads();
  if (tid == 0) {
    float aux = 0.f;
    int nt = 0, po = 0;
    for (int e = 0; e < NE; e++) {
      float ps = wps[0][e] + wps[1][e] + wps[2][e] + wps[3][e];
      aux += (float)scnt[e] * ps;
      meta->pad_off[e] = po;
      int pc = (scnt[e] + 127) & ~127;
      for (int i = 0; i < pc / 128; i++) {
        meta->tile_e[nt] = e; meta->tile_m0[nt] = po + i * 128; nt++;
      }
      po += pc;
    }
    meta->pad_off[NE] = po;
    meta->n_mtiles = nt;
    aux_out[0] = aux * (8.f / ((float)T_TOK * (float)T_TOK));
  }
}

// -------- deterministic scatter: one wave per expert, ballot-scan ----------
__global__ __launch_bounds__(64) void scatter_kernel(
    const int* __restrict__ topi, const float* __restrict__ topw,
    const Meta* __restrict__ meta,
    int* __restrict__ t_of, float* __restrict__ w_of, int* __restrict__ k_of) {
  int e = blockIdx.x, lane = threadIdx.x;
  int base = meta->pad_off[e];
  for (int c = 0; c < T_TOK * 2; c += 64) {
    int idx = c + lane;
    int sel = (topi[idx] == e) ? 1 : 0;
    unsigned long long mask = __ballot(sel);
    if (sel) {
      int rank = __popcll(mask & ((1ull << lane) - 1ull));
      int s = base + rank;
      t_of[s] = idx >> 1;
      k_of[s] = idx & 1;
      w_of[s] = topw[idx];
    }
    base += (int)__popcll(mask);
  }
}

// -------- gather tokens into bucket order, fp32 -> bf16 --------------------
__global__ __launch_bounds__(256) void gather_kernel(
    const float* __restrict__ x, const int* __restrict__ t_of,
    unsigned short* __restrict__ Xg_u) {
  int s = blockIdx.x;
  int t = t_of[s];
  if (t < 0) return;  // pad slot keeps 0xAA poison -> tiny bf16 value, harmless
  bf16* Xg = (bf16*)Xg_u;
  int i = threadIdx.x;
  float4 v = ((const float4*)(x + (size_t)t * DM))[i];
  bf16x4 o = {(bf16)v.x, (bf16)v.y, (bf16)v.z, (bf16)v.w};
  ((bf16x4*)(Xg + (size_t)s * DM))[i] = o;
}

// -------- transpose-convert: src fp32 [E][R][C] -> dst bf16 [E][C][R] ------
// 64x64 tile, float4 coalesced loads, bf16x8 (16B) coalesced stores.
// LDS pad 69: column reads are 2-way (free) bank pattern.
__global__ __launch_bounds__(256) void transpose_kernel(
    const float* __restrict__ src, unsigned short* __restrict__ dst_u, int R, int C) {
  bf16* dst = (bf16*)dst_u;
  int e = blockIdx.z;
  int c0 = blockIdx.x * 64, r0 = blockIdx.y * 64;
  __shared__ float tile[64][69];
  const float* s = src + (size_t)e * R * C;
  int lr = threadIdx.x >> 4;          // 0..15
  int lc4 = (threadIdx.x & 15) * 4;   // 0..60
#pragma unroll
  for (int p = 0; p < 4; p++) {
    float4 v = *(const float4*)&s[(size_t)(r0 + p * 16 + lr) * C + c0 + lc4];
    tile[p * 16 + lr][lc4]     = v.x;
    tile[p * 16 + lr][lc4 + 1] = v.y;
    tile[p * 16 + lr][lc4 + 2] = v.z;
    tile[p * 16 + lr][lc4 + 3] = v.w;
  }
  __syncthreads();
  bf16* d = dst + (size_t)e * C * R;
#pragma unroll
  for (int s2 = 0; s2 < 2; s2++) {
    int q = threadIdx.x + 256 * s2;   // 0..511
    int c = q >> 3;                   // 0..63 output row (= source col)
    int rs = (q & 7) * 8;             // 8-elem segment along source rows
    bf16x8 o;
#pragma unroll
    for (int j = 0; j < 8; j++) o[j] = (bf16)tile[rs + j][c];
    *(bf16x8*)&d[(size_t)(c0 + c) * R + r0 + rs] = o;
  }
}

// -------- async global -> LDS, 16B per lane --------------------------------
__device__ inline void gl_lds16(const void* g, void* l) {
  __builtin_amdgcn_global_load_lds(
      (const __attribute__((address_space(1))) unsigned int*)g,
      (__attribute__((address_space(3))) unsigned int*)l, 16, 0, 0);
}

// -------- grouped GEMM, 128x128 tile, BK=64, swizzled LDS, XCD swizzle -----
// MODE 1: h = relu(acc + b1) -> bf16 Hout
// MODE 2: y = (acc + (z==0 ? b2 : 0)) * gate -> fp32 Pz[kslot][t][DM]
// Block remap: xcd = id%8 owns bx in [xcd*9, xcd*9+9) (~= one expert), so each
// XCD's L2 sees one expert's A strip + B slab instead of the whole weight.
template <int MODE>
__global__ __launch_bounds__(256) void gemm_kernel(
    const unsigned short* __restrict__ A_u, const unsigned short* __restrict__ Bt_u,
    const float* __restrict__ bias, const Meta* __restrict__ meta,
    int Ktot, int Ksp, int N,
    unsigned short* __restrict__ Hout_u,
    float* __restrict__ P0, float* __restrict__ P1,
    const int* __restrict__ t_of, const int* __restrict__ k_of,
    const float* __restrict__ w_of) {
  // --- XCD-aware decode (gridDim.x == 72, divisible by 8) ---
  int id = blockIdx.x + gridDim.x * (blockIdx.y + gridDim.y * blockIdx.z);
  int xcd = id & 7;
  int rr = id >> 3;
  int chunk = gridDim.x >> 3;            // 9
  int bx = xcd * chunk + rr % chunk;
  int rest = rr / chunk;
  int n0 = (rest % gridDim.y) * 128;
  int bz = rest / gridDim.y;

  if (bx >= meta->n_mtiles) return;
  const bf16* A = (const bf16*)A_u;
  const bf16* Bt = (const bf16*)Bt_u;
  int e = meta->tile_e[bx];
  int m0 = meta->tile_m0[bx];
  int koff = bz * Ksp;
  const bf16* Be = Bt + (size_t)e * N * Ktot;

  __shared__ bf16 As[128 * 64];  // [row][k], granule-swizzled: p holds g = p^(row&7)
  __shared__ bf16 Bs[128 * 64];

  int tid = threadIdx.x, lane = tid & 63, wave = tid >> 6;
  int wr = wave >> 1, wc = wave & 1;
  int srow = lane >> 3;
  int sgran = lane & 7;
  int gcol = (sgran ^ srow) * 8;           // swizzled source column (elements)

  const bf16* Ag = A + (size_t)(m0 + wave * 8 + srow) * Ktot + koff + gcol;
  const bf16* Bg = Be + (size_t)(n0 + wave * 8 + srow) * Ktot + koff + gcol;
  bf16* AsW = As + wave * 512;
  bf16* BsW = Bs + wave * 512;

  f32x4 acc[4][4];
#pragma unroll
  for (int i = 0; i < 4; i++)
#pragma unroll
    for (int j = 0; j < 4; j++) acc[i][j] = (f32x4){0.f, 0.f, 0.f, 0.f};

  int fr = lane & 15;
  int qh = lane >> 4;
  int swz = fr & 7;

  for (int k0 = 0; k0 < Ksp; k0 += 64) {
#pragma unroll
    for (int r = 0; r < 4; r++) {
      gl_lds16(Ag + (size_t)(r * 32) * Ktot + k0, AsW + r * 2048);
      gl_lds16(Bg + (size_t)(r * 32) * Ktot + k0, BsW + r * 2048);
    }
    __syncthreads();
#pragma unroll
    for (int kk = 0; kk < 64; kk += 32) {
      int col = (((kk >> 3) | qh) ^ swz) * 8;
      bf16x8 af[4], bfr[4];
#pragma unroll
      for (int i = 0; i < 4; i++)
        af[i] = *(const bf16x8*)&As[(wr * 64 + i * 16 + fr) * 64 + col];
#pragma unroll
      for (int j = 0; j < 4; j++)
        bfr[j] = *(const bf16x8*)&Bs[(wc * 64 + j * 16 + fr) * 64 + col];
#pragma unroll
      for (int i = 0; i < 4; i++)
#pragma unroll
        for (int j = 0; j < 4; j++)
          acc[i][j] = __builtin_amdgcn_mfma_f32_16x16x32_bf16(af[i], bfr[j], acc[i][j], 0, 0, 0);
    }
    __syncthreads();
  }

  // epilogue; C/D layout: col = lane&15, row = (lane>>4)*4 + reg  [m89/m91]
  int crow = (lane >> 4) * 4;
  int ccol = lane & 15;
  if (MODE == 1) {
    bf16* Hout = (bf16*)Hout_u;
#pragma unroll
    for (int i = 0; i < 4; i++) {
#pragma unroll
      for (int r = 0; r < 4; r++) {
        int slot = m0 + wr * 64 + i * 16 + crow + r;
        bf16* hrow = Hout + (size_t)slot * N;
#pragma unroll
        for (int j = 0; j < 4; j++) {
          int n = n0 + wc * 64 + j * 16 + ccol;
          float v = acc[i][j][r] + bias[e * N + n];
          hrow[n] = (bf16)fmaxf(v, 0.f);
        }
      }
    }
  } else {
    float* Pz = (bz == 0) ? P0 : P1;
    int addb = (bz == 0) ? 1 : 0;
#pragma unroll
    for (int i = 0; i < 4; i++) {
#pragma unroll
      for (int r = 0; r < 4; r++) {
        int slot = m0 + wr * 64 + i * 16 + crow + r;
        int t = t_of[slot];
        if (t < 0) continue;
        int ks = k_of[slot];
        float w = w_of[slot];
        float* yrow = Pz + ((size_t)ks * T_TOK + t) * DM;
#pragma unroll
        for (int j = 0; j < 4; j++) {
          int n = n0 + wc * 64 + j * 16 + ccol;
          float bv = addb ? bias[e * DM + n] : 0.f;
          yrow[n] = (acc[i][j][r] + bv) * w;
        }
      }
    }
  }
}

// -------- residual + LayerNorm (sums 4 split-K partials) -------------------
__global__ __launch_bounds__(256) void ln_kernel(
    const float* __restrict__ x,
    const float* __restrict__ P0, const float* __restrict__ P1,
    const float* __restrict__ gamma, const float* __restrict__ beta,
    float* __restrict__ out) {
  int t = blockIdx.x, tid = threadIdx.x, lane = tid & 63, wave = tid >> 6;
  size_t row = (size_t)t * DM;
  size_t kstride = (size_t)T_TOK * DM;
  float4 a  = ((const float4*)(x + row))[tid];
  float4 y0 = ((const float4*)(P0 + row))[tid];
  float4 y1 = ((const float4*)(P0 + kstride + row))[tid];
  float4 y2 = ((const float4*)(P1 + row))[tid];
  float4 y3 = ((const float4*)(P1 + kstride + row))[tid];
  float4 sv;
  sv.x = a.x + y0.x + y1.x + y2.x + y3.x;
  sv.y = a.y + y0.y + y1.y + y2.y + y3.y;
  sv.z = a.z + y0.z + y1.z + y2.z + y3.z;
  sv.w = a.w + y0.w + y1.w + y2.w + y3.w;
  float sum = sv.x + sv.y + sv.z + sv.w;
  float sq = sv.x * sv.x + sv.y * sv.y + sv.z * sv.z + sv.w * sv.w;
#pragma unroll
  for (int off = 32; off >= 1; off >>= 1) {
    sum += __shfl_xor(sum, off);
    sq += __shfl_xor(sq, off);
  }
  __shared__ float ls[4], lq[4], stats[2];
  if (lane == 0) { ls[wave] = sum; lq[wave] = sq; }
  __syncthreads();
  if (tid == 0) {
    float ts = ls[0] + ls[1] + ls[2] + ls[3];
    float tq = lq[0] + lq[1] + lq[2] + lq[3];
    float mu = ts * (1.f / DM);
    float var = tq * (1.f / DM) - mu * mu;
    stats[0] = mu;
    stats[1] = rsqrtf(var + 1e-5f);
  }
  __syncthreads();
  float mu = stats[0], rs = stats[1];
  float4 g = ((const float4*)gamma)[tid];
  float4 b = ((const float4*)beta)[tid];
  float4 o;
  o.x = (sv.x - mu) * rs * g.x + b.x;
  o.y = (sv.y - mu) * rs * g.y + b.y;
  o.z = (sv.z - mu) * rs * g.z + b.z;
  o.w = (sv.w - mu) * rs * g.w + b.w;
  ((float4*)(out + row))[tid] = o;
}

// ---------------------------------------------------------------------------
extern "C" void kernel_launch(void* const* d_in, const int* in_sizes, int n_in,
                              void* d_out, int out_size, void* d_ws, size_t ws_size,
                              hipStream_t stream) {
  const float* x     = (const float*)d_in[0];
  const float* Wg    = (const float*)d_in[2];
  const float* W1    = (const float*)d_in[3];
  const float* b1    = (const float*)d_in[4];
  const float* W2    = (const float*)d_in[5];
  const float* b2    = (const float*)d_in[6];
  const float* gamma = (const float*)d_in[7];
  const float* beta  = (const float*)d_in[8];
  float* out = (float*)d_out;

  char* ws = (char*)d_ws;
  size_t off = 0;
  auto alloc = [&](size_t bytes) -> void* {
    off = (off + 4095) & ~(size_t)4095;
    void* p = ws + off;
    off += bytes;
    return p;
  };
  Meta* meta   = (Meta*)alloc(sizeof(Meta));
  int* topi    = (int*)alloc((size_t)T_TOK * 2 * 4);
  float* topw  = (float*)alloc((size_t)T_TOK * 2 * 4);
  float* probs = (float*)alloc((size_t)T_TOK * NE * 4);
  int* t_of    = (int*)alloc((size_t)CAP * 4);
  int* k_of    = (int*)alloc((size_t)CAP * 4);
  float* w_of  = (float*)alloc((size_t)CAP * 4);
  // Xg (18.9 MB) is dead after gemm1; its region doubles as split-1 partials
  size_t xg_bytes = (size_t)CAP * DM * 2;
  size_t p_bytes  = (size_t)2 * T_TOK * DM * 4;           // 33.6 MB
  char* xg_region = (char*)alloc(xg_bytes > p_bytes ? xg_bytes : p_bytes);
  unsigned short* Xg = (unsigned short*)xg_region;
  float* Psp1        = (float*)xg_region;
  unsigned short* Hbuf = (unsigned short*)alloc((size_t)CAP * DF * 2);    // 75.5 MB
  float* Psp0          = (float*)alloc(p_bytes);                           // 33.6 MB
  unsigned short* WT   = (unsigned short*)alloc((size_t)NE * DM * DF * 2); // 67.1 MB

  hipMemsetAsync(t_of, 0xFF, (size_t)CAP * 4, stream);

  router_kernel<<<dim3(T_TOK / 4), dim3(256), 0, stream>>>(x, Wg, topi, topw, probs);
  prep_kernel<<<dim3(1), dim3(256), 0, stream>>>(topi, probs, meta, out + (size_t)T_TOK * DM);
  scatter_kernel<<<dim3(NE), dim3(64), 0, stream>>>(topi, topw, meta, t_of, w_of, k_of);
  gather_kernel<<<dim3(CAP), dim3(256), 0, stream>>>(x, t_of, Xg);

  // W1 [E][DM][DF] -> W1T [E][DF][DM] (bf16, k-contiguous)
  transpose_kernel<<<dim3(DF / 64, DM / 64, NE), dim3(256), 0, stream>>>(W1, WT, DM, DF);
  gemm_kernel<1><<<dim3(MAXMT, DF / 128, 1), dim3(256), 0, stream>>>(
      Xg, WT, b1, meta, DM, DM, DF, Hbuf, (float*)nullptr, (float*)nullptr,
      (const int*)nullptr, (const int*)nullptr, (const float*)nullptr);

  // W2 [E][DF][DM] -> W2T [E][DM][DF] (reuses WT buffer after GEMM1)
  transpose_kernel<<<dim3(DM / 64, DF / 64, NE), dim3(256), 0, stream>>>(W2, WT, DF, DM);
  gemm_kernel<2><<<dim3(MAXMT, DM / 128, 2), dim3(256), 0, stream>>>(
      Hbuf, WT, b2, meta, DF, DF / 2, DM, (unsigned short*)nullptr, Psp0, Psp1,
      t_of, k_of, w_of);

  ln_kernel<<<dim3(T_TOK), dim3(256), 0, stream>>>(x, Psp0, Psp1, gamma, beta, out);
}